// Round 7
// baseline (1301.071 us; speedup 1.0000x reference)
//
#include <hip/hip_runtime.h>
#include <hip/hip_bf16.h>

#define HID 100
#define TT 750
#define NB_TOT 1024
#define ALPHA 0.01f
#define NSTD 0.1f

typedef __bf16 bf16x8 __attribute__((ext_vector_type(8)));
typedef float floatx4 __attribute__((ext_vector_type(4)));

__device__ __forceinline__ float fast_tanh(float v) {
    // tanh(v) = 1 - 2/(exp(2v)+1); graceful at +-inf, abs err ~1e-6
    float e = __expf(2.0f * v);
    return 1.0f - 2.0f / (e + 1.0f);
}

// Workgroup barrier WITHOUT the vmcnt(0) drain __syncthreads() emits:
// lgkmcnt(0) makes our ds ops visible; global prefetch stays in flight.
__device__ __forceinline__ void wg_barrier() {
    asm volatile("s_waitcnt lgkmcnt(0)" ::: "memory");
    __builtin_amdgcn_s_barrier();
    asm volatile("" ::: "memory");
    __builtin_amdgcn_sched_barrier(0);
}

struct Pf { float n0, n1; floatx4 u0, u1; };

// (512,2): guarantee only 2 waves/EU -> VGPR cap 256; kernel needs ~110,
// which still allows 16 waves/CU (m69) => the grid's 2 blocks/CU co-residency
// survives WITHOUT spilling. R6's (512,4) clamped VGPR=64 -> 1 MB of scratch.
__global__ __launch_bounds__(512, 2)
void rnn_kernel(const float* __restrict__ useq,   // [750][1024][4]
                const float* __restrict__ noise,  // [750][1024][100]
                const float* __restrict__ Jw,     // [100][100]
                const float* __restrict__ Bm,     // [4][100]
                const float* __restrict__ cxp,    // [100]
                const float* __restrict__ Ww,     // [100]
                const float* __restrict__ Wb,     // [1]
                float* __restrict__ out)          // [1024]
{
    // Double-buffered r: [buf][2 rows][128 bf16], 16B-chunk XOR swizzle
    // (phys chunk = (k>>3)^row). A rows 2..15 of the MFMA read row (m16&1)
    // data (finite, harmless: C rows 2..15 never consumed). k in [100,128)
    // stays zero from init; J is zero-padded there anyway.
    __shared__ __align__(16) __bf16 rbuf[2][2][128];
    __shared__ float red[2][112];

    const int tid  = threadIdx.x;
    const int wv   = tid >> 6;      // 0..7 — wave wv owns N-tile wv
    const int lane = tid & 63;
    const int m16  = lane & 15;
    const int q    = lane >> 4;
    const int wg   = blockIdx.x;
    const int gb0  = wg * 2;

    // C-layout (16x16x32): col=lane&15, row=(lane>>4)*4+reg. Batches = rows
    // 0,1 -> q==0 lanes, regs 0,1. Update happens there, in registers.
    const int  hh  = wv * 16 + m16;
    const bool act = (q == 0) && (hh < HID);

    // zero both r buffers: 2*2*128*2B = 1024 B = 256 dwords
    if (tid < 256) ((float*)rbuf)[tid] = 0.0f;

    // --- J fragments (B operand) for tile wv, hi/lo bf16 split ---
    // B layout: col = lane&15 -> J row hh; k = s*32 + q*8 + j
    bf16x8 jhi[4], jlo[4];
    #pragma unroll
    for (int s = 0; s < 4; ++s) {
        bf16x8 vh, vl;
        #pragma unroll
        for (int j = 0; j < 8; ++j) {
            const int k = s * 32 + q * 8 + j;
            float v = (hh < HID && k < HID) ? Jw[hh * HID + k] : 0.0f;
            __bf16 hi = (__bf16)v;
            vh[j] = hi;
            vl[j] = (__bf16)(v - (float)hi);
        }
        jhi[s] = vh; jlo[s] = vl;
    }

    floatx4 bm = {0,0,0,0};
    float cx = 0.f, w = 0.f;
    if (act) {
        bm = floatx4{Bm[0*HID+hh], Bm[1*HID+hh], Bm[2*HID+hh], Bm[3*HID+hh]};
        cx = cxp[hh]; w = Ww[hh];
    }

    // --- prefetch (depth 4); batch1 via imm offsets (+400B / +16B) ---
    const float* np = noise + (size_t)gb0 * HID + (hh < HID ? hh : 0);
    const float* up = useq  + (size_t)gb0 * 4;

    auto pfetch = [&](int t, Pf& P) {
        const float* n = np + (size_t)t * (NB_TOT * HID);
        const float* u = up + (size_t)t * (NB_TOT * 4);
        P.n0 = n[0];  P.n1 = n[HID];
        P.u0 = *(const floatx4*)u;
        P.u1 = *(const floatx4*)(u + 4);
    };

    Pf p0, p1, p2, p3;
    if (act) { pfetch(0, p0); pfetch(1, p1); pfetch(2, p2); pfetch(3, p3); }

    float x0 = 0.f, x1 = 0.f;
    __syncthreads();   // once before the loop

    // A-frag read: row clamped to m16&1 (rows 2..15 get copies — harmless),
    // chunk (s*4+q) XOR row key. 8 distinct 16B addrs -> broadcast, ~2-way.
    const int arow = m16 & 1;

    auto step = [&](int T, Pf& P, int pb) {
        // ---- A-frags: 4 x ds_read_b128 from rbuf[pb] ----
        const bf16x8* rb = (const bf16x8*)(rbuf[pb]);
        bf16x8 afr[4];
        #pragma unroll
        for (int s = 0; s < 4; ++s)
            afr[s] = rb[arow * 16 + ((s * 4 + q) ^ arow)];
        // ---- base precompute (off critical path: inputs are 4 steps old) ----
        float base0 = 0.f, base1 = 0.f;
        if (act) {
            const float d0 = P.u0[0]*bm[0] + P.u0[1]*bm[1] + P.u0[2]*bm[2] + P.u0[3]*bm[3];
            const float d1 = P.u1[0]*bm[0] + P.u1[1]*bm[1] + P.u1[2]*bm[2] + P.u1[3]*bm[3];
            base0 = x0 * (1.0f - ALPHA) + ALPHA * (d0 + cx + NSTD * P.n0);
            base1 = x1 * (1.0f - ALPHA) + ALPHA * (d1 + cx + NSTD * P.n1);
        }
        // ---- MFMA: 4 independent chains, depth 2 ----
        floatx4 hA = {0,0,0,0}, hB = {0,0,0,0}, lA = {0,0,0,0}, lB = {0,0,0,0};
        hA = __builtin_amdgcn_mfma_f32_16x16x32_bf16(afr[0], jhi[0], hA, 0, 0, 0);
        lA = __builtin_amdgcn_mfma_f32_16x16x32_bf16(afr[0], jlo[0], lA, 0, 0, 0);
        hB = __builtin_amdgcn_mfma_f32_16x16x32_bf16(afr[2], jhi[2], hB, 0, 0, 0);
        lB = __builtin_amdgcn_mfma_f32_16x16x32_bf16(afr[2], jlo[2], lB, 0, 0, 0);
        hA = __builtin_amdgcn_mfma_f32_16x16x32_bf16(afr[1], jhi[1], hA, 0, 0, 0);
        lA = __builtin_amdgcn_mfma_f32_16x16x32_bf16(afr[1], jlo[1], lA, 0, 0, 0);
        hB = __builtin_amdgcn_mfma_f32_16x16x32_bf16(afr[3], jhi[3], hB, 0, 0, 0);
        lB = __builtin_amdgcn_mfma_f32_16x16x32_bf16(afr[3], jlo[3], lB, 0, 0, 0);
        // ---- in-register update + r write into rbuf[pb^1] ----
        if (act) {
            const float y0 = (hA[0] + hB[0]) + (lA[0] + lB[0]);
            const float y1 = (hA[1] + hB[1]) + (lA[1] + lB[1]);
            x0 = base0 + ALPHA * y0;
            x1 = base1 + ALPHA * y1;
            __bf16* wb = (__bf16*)(rbuf[pb ^ 1]);
            const int c = hh >> 3, e = hh & 7;
            wb[hh]                        = (__bf16)fast_tanh(x0);  // row 0: c^0
            wb[128 + ((c ^ 1) << 3) + e]  = (__bf16)fast_tanh(x1);  // row 1
            // refill prefetch slot (uniform cond; stays in flight across barrier)
            if (T + 4 < TT) pfetch(T + 4, P);
        }
        wg_barrier();   // ONE barrier per step
    };

    for (int tb = 0; tb < 748; tb += 4) {
        step(tb + 0, p0, 0);
        step(tb + 1, p1, 1);
        step(tb + 2, p2, 0);
        step(tb + 3, p3, 1);
    }
    step(748, p0, 0);
    step(749, p1, 1);

    // ---- epilogue: out[b] = sum_h tanh(x_final)*Wout[h] + Wout_b ----
    if (act) {
        red[0][hh] = fast_tanh(x0) * w;
        red[1][hh] = fast_tanh(x1) * w;
    }
    __syncthreads();
    if (tid < 2) {
        float s2 = Wb[0];
        #pragma unroll 4
        for (int i = 0; i < HID; ++i) s2 += red[tid][i];
        out[gb0 + tid] = s2;
    }
}

extern "C" void kernel_launch(void* const* d_in, const int* in_sizes, int n_in,
                              void* d_out, int out_size, void* d_ws, size_t ws_size,
                              hipStream_t stream) {
    rnn_kernel<<<dim3(512), dim3(512), 0, stream>>>(
        (const float*)d_in[0], (const float*)d_in[1], (const float*)d_in[2],
        (const float*)d_in[3], (const float*)d_in[4], (const float*)d_in[5],
        (const float*)d_in[6], (float*)d_out);
}

// Round 8
// 822.064 us; speedup vs baseline: 1.5827x; 1.5827x over previous
//
#include <hip/hip_runtime.h>
#include <hip/hip_bf16.h>

#define HID 100
#define TT 750
#define NB_TOT 1024
#define ALPHA 0.01f
#define NSTD 0.1f

typedef __bf16 bf16x8 __attribute__((ext_vector_type(8)));
typedef float floatx4 __attribute__((ext_vector_type(4)));

__device__ __forceinline__ float fast_tanh(float v) {
    // tanh(v) = 1 - 2/(exp(2v)+1); graceful at +-inf, abs err ~1e-6
    float e = __expf(2.0f * v);
    return 1.0f - 2.0f / (e + 1.0f);
}

// Workgroup barrier WITHOUT the vmcnt(0) drain __syncthreads() emits:
// lgkmcnt(0) makes our ds ops visible; global prefetch stays in flight.
__device__ __forceinline__ void wg_barrier() {
    asm volatile("s_waitcnt lgkmcnt(0)" ::: "memory");
    __builtin_amdgcn_s_barrier();
    asm volatile("" ::: "memory");
    __builtin_amdgcn_sched_barrier(0);
}

struct Pf { float n; floatx4 u; };

// 256-thread shell: resource behavior proven across R0-R5 (VGPR ~100 ok,
// 2 blocks/CU co-resident at (256,2)). Do NOT use 512-thread blocks (R6/R7).
__global__ __launch_bounds__(256, 2)
void rnn_kernel(const float* __restrict__ useq,   // [750][1024][4]
                const float* __restrict__ noise,  // [750][1024][100]
                const float* __restrict__ Jw,     // [100][100]
                const float* __restrict__ Bm,     // [4][100]
                const float* __restrict__ cxp,    // [100]
                const float* __restrict__ Ww,     // [100]
                const float* __restrict__ Wb,     // [1]
                float* __restrict__ out)          // [1024]
{
    // Double-buffered r: [buf][2 rows][128 bf16], 16B-chunk XOR swizzle
    // (logical chunk c of row b stored at phys chunk c^b). MFMA A-rows are
    // clamped to m16&1 => C row m = y[m&1][col]: EVERY 16-lane group holds
    // y[b0],y[b1] in regs 0,1 — update is fully distributed, no ybuf/shfl.
    __shared__ __align__(16) __bf16 rbuf[2][2][128];
    __shared__ float red[2][112];

    const int tid  = threadIdx.x;
    const int wv   = tid >> 6;      // wave: owns tiles 2wv (A), 2wv+1 (B)
    const int lane = tid & 63;
    const int m16  = lane & 15;
    const int q    = lane >> 4;     // lane group 0..3
    const int wg   = blockIdx.x;
    const int gb0  = wg * 2;

    // lane's update assignment: batch = q&1, tile = A or B by q>>1
    const int  b    = q & 1;
    const int  tsB  = q >> 1;                    // 0 -> tileA, 1 -> tileB
    const int  tile = wv * 2 + tsB;
    const int  hh   = tile * 16 + m16;
    const bool v    = (hh < HID);
    const int  hc   = v ? hh : 0;

    // zero both r buffers: 2*2*128*2B = 1024 B = 256 dwords
    ((float*)rbuf)[tid] = 0.0f;

    // --- J fragments (B operand) for tiles 2wv, 2wv+1; K=96 in MFMA ---
    // B layout: col = lane&15 -> J row; k = s*32 + q*8 + j
    bf16x8 jhi[2][3], jlo[2][3];
    #pragma unroll
    for (int ti = 0; ti < 2; ++ti) {
        const int ht = (wv * 2 + ti) * 16 + m16;
        #pragma unroll
        for (int s = 0; s < 3; ++s) {
            bf16x8 vh, vl;
            #pragma unroll
            for (int j = 0; j < 8; ++j) {
                const int k = s * 32 + q * 8 + j;
                float jv = (ht < HID) ? Jw[ht * HID + k] : 0.0f;
                __bf16 hi = (__bf16)jv;
                vh[j] = hi;
                vl[j] = (__bf16)(jv - (float)hi);
            }
            jhi[ti][s] = vh; jlo[ti][s] = vl;
        }
    }

    // --- k=96..99 tail J (fp32, exact) + per-h constants for this lane ---
    float jt0 = 0.f, jt1 = 0.f, jt2 = 0.f, jt3 = 0.f;
    floatx4 bm = {0,0,0,0};
    float cx = 0.f, w = 0.f;
    if (v) {
        jt0 = Jw[hc * HID + 96]; jt1 = Jw[hc * HID + 97];
        jt2 = Jw[hc * HID + 98]; jt3 = Jw[hc * HID + 99];
        bm = floatx4{Bm[0*HID+hc], Bm[1*HID+hc], Bm[2*HID+hc], Bm[3*HID+hc]};
        cx = cxp[hc]; w = Ww[hc];
    }

    // --- prefetch (depth 4): one noise scalar + one u float4 per lane ---
    const float* np = noise + (size_t)(gb0 + b) * HID + hc;
    const float* up = useq  + (size_t)(gb0 + b) * 4;

    auto pfetch = [&](int t, Pf& P) {
        P.n = np[(size_t)t * (NB_TOT * HID)];
        P.u = *(const floatx4*)(up + (size_t)t * (NB_TOT * 4));
    };

    Pf p0, p1, p2, p3;
    if (v) { pfetch(0, p0); pfetch(1, p1); pfetch(2, p2); pfetch(3, p3); }

    float x = 0.0f;
    __syncthreads();   // once before the loop

    // A-frag read: row clamped to m16&1; chunk (s*4+q)^arow (range 0..11).
    // 8 distinct 16B addrs per instr -> broadcast, ~2-way (free).
    const int arow = m16 & 1;
    // tail r elements: logical k-chunk 12 of row b at phys chunk 12^b:
    // b0 -> element 96 (byte 192), b1 -> element 128+104=232 (byte 464)
    const int toff = b ? 232 : 96;
    // r write address (elements): row b, phys chunk (hh>>3)^b
    const int woff = b * 128 + (((hh >> 3) ^ b) << 3) + (hh & 7);

    auto step = [&](int T, Pf& P, int pb) {
        const __bf16* rbb = (const __bf16*)rbuf[pb];
        const bf16x8* rb  = (const bf16x8*)rbb;
        bf16x8 afr[3];
        #pragma unroll
        for (int s = 0; s < 3; ++s)
            afr[s] = rb[arow * 16 + ((s * 4 + q) ^ arow)];
        const uint2 tr = *(const uint2*)(rbb + toff);   // r[b][96..99]
        // ---- base precompute (prefetched data is 4 steps old: ready) ----
        float base = 0.f;
        if (v) {
            const float r96 = __uint_as_float((tr.x & 0xffffu) << 16);
            const float r97 = __uint_as_float(tr.x & 0xffff0000u);
            const float r98 = __uint_as_float((tr.y & 0xffffu) << 16);
            const float r99 = __uint_as_float(tr.y & 0xffff0000u);
            const float tdot = r96*jt0 + r97*jt1 + r98*jt2 + r99*jt3;
            const float d = P.u[0]*bm[0] + P.u[1]*bm[1] + P.u[2]*bm[2] + P.u[3]*bm[3];
            base = x * (1.0f - ALPHA) + ALPHA * (d + cx + NSTD * P.n + tdot);
        }
        // ---- MFMA: K=96, 4 independent chains of depth 3 ----
        floatx4 hA = {0,0,0,0}, lA = {0,0,0,0}, hB = {0,0,0,0}, lB = {0,0,0,0};
        hA = __builtin_amdgcn_mfma_f32_16x16x32_bf16(afr[0], jhi[0][0], hA, 0, 0, 0);
        lA = __builtin_amdgcn_mfma_f32_16x16x32_bf16(afr[0], jlo[0][0], lA, 0, 0, 0);
        hB = __builtin_amdgcn_mfma_f32_16x16x32_bf16(afr[0], jhi[1][0], hB, 0, 0, 0);
        lB = __builtin_amdgcn_mfma_f32_16x16x32_bf16(afr[0], jlo[1][0], lB, 0, 0, 0);
        hA = __builtin_amdgcn_mfma_f32_16x16x32_bf16(afr[1], jhi[0][1], hA, 0, 0, 0);
        lA = __builtin_amdgcn_mfma_f32_16x16x32_bf16(afr[1], jlo[0][1], lA, 0, 0, 0);
        hB = __builtin_amdgcn_mfma_f32_16x16x32_bf16(afr[1], jhi[1][1], hB, 0, 0, 0);
        lB = __builtin_amdgcn_mfma_f32_16x16x32_bf16(afr[1], jlo[1][1], lB, 0, 0, 0);
        hA = __builtin_amdgcn_mfma_f32_16x16x32_bf16(afr[2], jhi[0][2], hA, 0, 0, 0);
        lA = __builtin_amdgcn_mfma_f32_16x16x32_bf16(afr[2], jlo[0][2], lA, 0, 0, 0);
        hB = __builtin_amdgcn_mfma_f32_16x16x32_bf16(afr[2], jhi[1][2], hB, 0, 0, 0);
        lB = __builtin_amdgcn_mfma_f32_16x16x32_bf16(afr[2], jlo[1][2], lB, 0, 0, 0);
        // ---- distributed update: 1 state per lane ----
        if (v) {
            const float yA0 = hA[0] + lA[0], yA1 = hA[1] + lA[1];
            const float yB0 = hB[0] + lB[0], yB1 = hB[1] + lB[1];
            const float y = tsB ? (b ? yB1 : yB0) : (b ? yA1 : yA0);
            x = base + ALPHA * y;
            ((__bf16*)rbuf[pb ^ 1])[woff] = (__bf16)fast_tanh(x);
            if (T + 4 < TT) pfetch(T + 4, P);   // stays in flight across barrier
        }
        wg_barrier();   // ONE barrier per step
    };

    for (int tb = 0; tb < 748; tb += 4) {
        step(tb + 0, p0, 0);
        step(tb + 1, p1, 1);
        step(tb + 2, p2, 0);
        step(tb + 3, p3, 1);
    }
    step(748, p0, 0);
    step(749, p1, 1);

    // ---- epilogue: out[b] = sum_h tanh(x_final)*Wout[h] + Wout_b ----
    if (v) red[b][hh] = fast_tanh(x) * w;
    __syncthreads();
    if (tid < 2) {
        float s2 = Wb[0];
        #pragma unroll 4
        for (int i = 0; i < HID; ++i) s2 += red[tid][i];
        out[gb0 + tid] = s2;
    }
}

extern "C" void kernel_launch(void* const* d_in, const int* in_sizes, int n_in,
                              void* d_out, int out_size, void* d_ws, size_t ws_size,
                              hipStream_t stream) {
    rnn_kernel<<<dim3(512), dim3(256), 0, stream>>>(
        (const float*)d_in[0], (const float*)d_in[1], (const float*)d_in[2],
        (const float*)d_in[3], (const float*)d_in[4], (const float*)d_in[5],
        (const float*)d_in[6], (float*)d_out);
}